// Round 8
// baseline (698.461 us; speedup 1.0000x reference)
//
#include <hip/hip_runtime.h>
#include <stdint.h>

// Binarized MLP forward, MI355X.
// GEMMs: m201-faithful 256x256 tile, BK=64, 8 waves (2M x 4N, interleaved
// 16-col/16-row wave mapping), 4 phases/K-tile, barrier-pair + setprio per
// phase, counted vmcnt(4) (never drains in main loop), 3-bit XOR LDS swizzle
// (pre-swizzled global source, rule #21). Fused BN-stats epilogue.

using u16 = unsigned short;
typedef u16 u16x8 __attribute__((ext_vector_type(8)));
typedef __bf16 bf16x8 __attribute__((ext_vector_type(8)));
typedef float f32x4 __attribute__((ext_vector_type(4)));

#define NB 32768
#define KP1 1664   // 784*2 = 1568 padded to 26*64
#define K2 2048

__device__ __forceinline__ u16 f2bf(float f) {
  uint32_t u = __float_as_uint(f);
  u += 0x7FFF + ((u >> 16) & 1);  // round-to-nearest-even
  return (u16)(u >> 16);
}
__device__ __forceinline__ float bf2f(u16 h) {
  return __uint_as_float(((uint32_t)h) << 16);
}

__device__ __forceinline__ void gload_lds16(const void* g, void* l) {
  __builtin_amdgcn_global_load_lds(
      (const __attribute__((address_space(1))) uint32_t*)g,
      (__attribute__((address_space(3))) uint32_t*)l, 16, 0, 0);
}

// x [NB,784] fp32 -> xhl [NB,1664] bf16 (hi,lo interleaved, cols 1568.. zero)
__global__ void prep_x_kernel(const float* __restrict__ x, u16* __restrict__ xhl) {
  int gid = blockIdx.x * 256 + threadIdx.x;  // NB*208 threads
  int row = gid / 208, slot = gid % 208;
  u16x8 o = {0, 0, 0, 0, 0, 0, 0, 0};
  if (slot < 196) {
    float4 v = *reinterpret_cast<const float4*>(x + (size_t)row * 784 + slot * 4);
    float vv[4] = {v.x, v.y, v.z, v.w};
#pragma unroll
    for (int e = 0; e < 4; ++e) {
      u16 hi = f2bf(vv[e]);
      u16 lo = f2bf(vv[e] - bf2f(hi));
      o[2 * e] = hi;
      o[2 * e + 1] = lo;
    }
  }
  *reinterpret_cast<u16x8*>(xhl + (size_t)row * KP1 + slot * 8) = o;
}

// W [rows, in_slots*4] fp32 -> sign duplicated [rows, out_slots*8] bf16
__global__ void prep_wdup_kernel(const float* __restrict__ w, u16* __restrict__ o,
                                 int in_slots, int out_slots) {
  int gid = blockIdx.x * 256 + threadIdx.x;
  int row = gid / out_slots, slot = gid % out_slots;
  u16x8 r = {0, 0, 0, 0, 0, 0, 0, 0};
  if (slot < in_slots) {
    float4 v = *reinterpret_cast<const float4*>(w + (size_t)row * (in_slots * 4) + slot * 4);
    float vv[4] = {v.x, v.y, v.z, v.w};
#pragma unroll
    for (int e = 0; e < 4; ++e) {
      u16 s = vv[e] > 0.f ? (u16)0x3F80 : (vv[e] < 0.f ? (u16)0xBF80 : (u16)0);
      r[2 * e] = s;
      r[2 * e + 1] = s;
    }
  }
  *reinterpret_cast<u16x8*>(o + (size_t)row * (out_slots * 8) + slot * 8) = r;
}

// ds_read_b128 with literal offset
#define DSR(D, A, OFF) \
  asm volatile("ds_read_b128 %0, %1 offset:%c2" : "=v"(D) : "v"(A), "i"(OFF))

#define VW(N) asm volatile("s_waitcnt vmcnt(" #N ")" ::: "memory")
#define NOPS do {} while (0)

// Stage A-half MH (128 rows x 64 cols, 2 gloads/thread) of K-tile TT into
// LDS buffer at byte offset OB. Dest linear; source col pre-swizzled
// (slot ^= row&7 realized as colL = 8*((lane&7)^(lane>>3)), rule #21).
#define STAGE_A(OB, MH, TT)                                                    \
  do {                                                                         \
    const char* _s = sA0 + (size_t)(MH) * 256 * (size_t)K + (size_t)(TT)*128;  \
    gload_lds16(_s, smem + (OB) + (MH)*16384 + w * 1024);                      \
    gload_lds16(_s + (size_t)128 * (size_t)K,                                  \
                smem + (OB) + (MH)*16384 + 8192 + w * 1024);                   \
  } while (0)
#define STAGE_B(OB, NH, TT)                                                    \
  do {                                                                         \
    const char* _s = sB0 + (size_t)(NH) * 256 * (size_t)K + (size_t)(TT)*128;  \
    gload_lds16(_s, smem + (OB) + 32768 + (NH)*16384 + w * 1024);              \
    gload_lds16(_s + (size_t)128 * (size_t)K,                                  \
                smem + (OB) + 32768 + (NH)*16384 + 8192 + w * 1024);           \
  } while (0)

// One m201-style phase: 12 ds_read_b128 (C-quadrant MH,NH) || stage issue ||
// counted vmcnt, then barrier / lgkmcnt(0) / sched_barrier (rule #18) /
// setprio-wrapped 16 MFMA / barrier.
#define PHASE(MH, NH, PRE, VWT)                                                           \
  do {                                                                                    \
    bf16x8 fa00, fa01, fa10, fa11, fa20, fa21, fa30, fa31, fb00, fb01, fb10, fb11;        \
    DSR(fa00, aA0, (MH)*16384 + 0);                                                       \
    DSR(fa01, aA1, (MH)*16384 + 0);                                                       \
    DSR(fa10, aA0, (MH)*16384 + 4096);                                                    \
    DSR(fa11, aA1, (MH)*16384 + 4096);                                                    \
    DSR(fa20, aA0, (MH)*16384 + 8192);                                                    \
    DSR(fa21, aA1, (MH)*16384 + 8192);                                                    \
    DSR(fa30, aA0, (MH)*16384 + 12288);                                                   \
    DSR(fa31, aA1, (MH)*16384 + 12288);                                                   \
    DSR(fb00, aB0, (NH)*16384 + 0);                                                       \
    DSR(fb01, aB1, (NH)*16384 + 0);                                                       \
    DSR(fb10, aB0, (NH)*16384 + 8192);                                                    \
    DSR(fb11, aB1, (NH)*16384 + 8192);                                                    \
    PRE;                                                                                  \
    VWT;                                                                                  \
    __builtin_amdgcn_s_barrier();                                                         \
    asm volatile("s_waitcnt lgkmcnt(0)" ::: "memory");                                    \
    __builtin_amdgcn_sched_barrier(0);                                                    \
    __builtin_amdgcn_s_setprio(1);                                                        \
    acc[(MH)*4 + 0][(NH)*2 + 0] = __builtin_amdgcn_mfma_f32_16x16x32_bf16(fa00, fb00, acc[(MH)*4 + 0][(NH)*2 + 0], 0, 0, 0); \
    acc[(MH)*4 + 0][(NH)*2 + 1] = __builtin_amdgcn_mfma_f32_16x16x32_bf16(fa00, fb10, acc[(MH)*4 + 0][(NH)*2 + 1], 0, 0, 0); \
    acc[(MH)*4 + 1][(NH)*2 + 0] = __builtin_amdgcn_mfma_f32_16x16x32_bf16(fa10, fb00, acc[(MH)*4 + 1][(NH)*2 + 0], 0, 0, 0); \
    acc[(MH)*4 + 1][(NH)*2 + 1] = __builtin_amdgcn_mfma_f32_16x16x32_bf16(fa10, fb10, acc[(MH)*4 + 1][(NH)*2 + 1], 0, 0, 0); \
    acc[(MH)*4 + 2][(NH)*2 + 0] = __builtin_amdgcn_mfma_f32_16x16x32_bf16(fa20, fb00, acc[(MH)*4 + 2][(NH)*2 + 0], 0, 0, 0); \
    acc[(MH)*4 + 2][(NH)*2 + 1] = __builtin_amdgcn_mfma_f32_16x16x32_bf16(fa20, fb10, acc[(MH)*4 + 2][(NH)*2 + 1], 0, 0, 0); \
    acc[(MH)*4 + 3][(NH)*2 + 0] = __builtin_amdgcn_mfma_f32_16x16x32_bf16(fa30, fb00, acc[(MH)*4 + 3][(NH)*2 + 0], 0, 0, 0); \
    acc[(MH)*4 + 3][(NH)*2 + 1] = __builtin_amdgcn_mfma_f32_16x16x32_bf16(fa30, fb10, acc[(MH)*4 + 3][(NH)*2 + 1], 0, 0, 0); \
    acc[(MH)*4 + 0][(NH)*2 + 0] = __builtin_amdgcn_mfma_f32_16x16x32_bf16(fa01, fb01, acc[(MH)*4 + 0][(NH)*2 + 0], 0, 0, 0); \
    acc[(MH)*4 + 0][(NH)*2 + 1] = __builtin_amdgcn_mfma_f32_16x16x32_bf16(fa01, fb11, acc[(MH)*4 + 0][(NH)*2 + 1], 0, 0, 0); \
    acc[(MH)*4 + 1][(NH)*2 + 0] = __builtin_amdgcn_mfma_f32_16x16x32_bf16(fa11, fb01, acc[(MH)*4 + 1][(NH)*2 + 0], 0, 0, 0); \
    acc[(MH)*4 + 1][(NH)*2 + 1] = __builtin_amdgcn_mfma_f32_16x16x32_bf16(fa11, fb11, acc[(MH)*4 + 1][(NH)*2 + 1], 0, 0, 0); \
    acc[(MH)*4 + 2][(NH)*2 + 0] = __builtin_amdgcn_mfma_f32_16x16x32_bf16(fa21, fb01, acc[(MH)*4 + 2][(NH)*2 + 0], 0, 0, 0); \
    acc[(MH)*4 + 2][(NH)*2 + 1] = __builtin_amdgcn_mfma_f32_16x16x32_bf16(fa21, fb11, acc[(MH)*4 + 2][(NH)*2 + 1], 0, 0, 0); \
    acc[(MH)*4 + 3][(NH)*2 + 0] = __builtin_amdgcn_mfma_f32_16x16x32_bf16(fa31, fb01, acc[(MH)*4 + 3][(NH)*2 + 0], 0, 0, 0); \
    acc[(MH)*4 + 3][(NH)*2 + 1] = __builtin_amdgcn_mfma_f32_16x16x32_bf16(fa31, fb11, acc[(MH)*4 + 3][(NH)*2 + 1], 0, 0, 0); \
    __builtin_amdgcn_s_setprio(0);                                                        \
    __builtin_amdgcn_s_barrier();                                                         \
  } while (0)

// C[M,N] = A[M,K]*Bm[N,K]^T, bf16 in fp32 out, 256x256 tile, 8 waves (2x4
// interleaved: wave rows mf*32+wr*16, cols nf*64+wc*16). LDS 128 KiB =
// 2 buffers x (A 2x16KB halves + B 2x16KB halves). Fused col-stats epilogue.
template <int RELU>
__launch_bounds__(512, 2) __global__
void gemm256_kernel(const u16* __restrict__ A, const u16* __restrict__ Bm,
                    float* __restrict__ C, float* __restrict__ st,
                    int M, int N, int K, int nbn) {
  extern __shared__ char smem[];
  typedef __attribute__((address_space(3))) char lds_char;
  const uint32_t ldsbase = (uint32_t)(uintptr_t)(lds_char*)smem;
  const int tid = threadIdx.x;
  const int lane = tid & 63;
  const int w = tid >> 6;
  const int wr = w >> 2;  // 0..1
  const int wc = w & 3;   // 0..3
  const int cpx = gridDim.x >> 3;
  const int bid = (blockIdx.x & 7) * cpx + (blockIdx.x >> 3);
  const int m0 = (bid / nbn) * 256;
  const int n0 = (bid % nbn) * 256;
  const int nt = K >> 6;  // BK=64 tiles

  f32x4 acc[8][4];
  const f32x4 z4 = {0.f, 0.f, 0.f, 0.f};
#pragma unroll
  for (int i = 0; i < 8; ++i)
#pragma unroll
    for (int j = 0; j < 4; ++j) acc[i][j] = z4;

  // staging source pointers (row w*8 + lane/8 within 64-row round, col
  // slot pre-swizzled by row&7)
  const int colL = 8 * ((lane & 7) ^ (lane >> 3));  // elements
  const char* sA0 = (const char*)(A + (size_t)(m0 + w * 8 + (lane >> 3)) * K + colL);
  const char* sB0 = (const char*)(Bm + (size_t)(n0 + w * 8 + (lane >> 3)) * K + colL);

  // read-side per-lane bases; kh-half toggles via addr^64 (slot bit2 XOR)
  const int lr = lane & 15;
  const uint32_t koff0 = (uint32_t)((((lane >> 4) ^ (lane & 7)) & 7) * 16);
  const uint32_t abase = (uint32_t)(wr * 2048 + lr * 128) + koff0;
  const uint32_t bbase = 32768u + (uint32_t)(wc * 2048 + lr * 128) + koff0;

  // prologue: stage tile 0 (issue order A0,B0,B1,A1), wait for A0+B0
  STAGE_A(0, 0, 0);
  STAGE_B(0, 0, 0);
  STAGE_B(0, 1, 0);
  STAGE_A(0, 1, 0);
  VW(4);
  __builtin_amdgcn_s_barrier();

  for (int t = 0; t + 1 < nt; ++t) {
    const uint32_t bufb = ldsbase + (uint32_t)((t & 1) << 16);
    const int ob = ((t + 1) & 1) << 16;
    const int tt = t + 1;
    const uint32_t aA0 = bufb + abase;
    const uint32_t aA1 = aA0 ^ 64u;
    const uint32_t aB0 = bufb + bbase;
    const uint32_t aB1 = aB0 ^ 64u;
    // ledger (2 loads/half, issue order A0,B0,B1,A1 one tile ahead):
    // p1 wait covers B1(t); p2 covers A1(t); p4 covers A0,B0(t+1).
    PHASE(0, 0, STAGE_A(ob, 0, tt), VW(4));
    PHASE(0, 1, STAGE_B(ob, 0, tt), VW(4));
    PHASE(1, 0, STAGE_B(ob, 1, tt), NOPS);
    PHASE(1, 1, STAGE_A(ob, 1, tt), VW(4));
  }
  {  // last tile: no staging; drain tail 2/0
    const uint32_t bufb = ldsbase + (uint32_t)(((nt - 1) & 1) << 16);
    const uint32_t aA0 = bufb + abase;
    const uint32_t aA1 = aA0 ^ 64u;
    const uint32_t aB0 = bufb + bbase;
    const uint32_t aB1 = aB0 ^ 64u;
    PHASE(0, 0, NOPS, VW(2));
    PHASE(0, 1, NOPS, VW(0));
    PHASE(1, 0, NOPS, NOPS);
    PHASE(1, 1, NOPS, NOPS);
  }

  // epilogue: C-write + fused column stats.
  // C/D layout (m89-verified): col-lane = lane&15, row = (lane>>4)*4 + i.
  // acc[i8][j]: row = (i8>>2)*128 + (i8&3)*32 + wr*16; col = (j>>1)*128 +
  // (j&1)*64 + wc*16.
  const int rq = lane >> 4;
  float cs[4] = {0.f, 0.f, 0.f, 0.f};
  float cq[4] = {0.f, 0.f, 0.f, 0.f};
#pragma unroll
  for (int i8 = 0; i8 < 8; ++i8)
#pragma unroll
    for (int j = 0; j < 4; ++j)
#pragma unroll
      for (int ii = 0; ii < 4; ++ii) {
        int r = m0 + (i8 >> 2) * 128 + (i8 & 3) * 32 + wr * 16 + rq * 4 + ii;
        int cc = n0 + (j >> 1) * 128 + (j & 1) * 64 + wc * 16 + lr;
        float v = acc[i8][j][ii];
        if (RELU) v = fmaxf(v, 0.f);
        C[(size_t)r * N + cc] = v;
        cs[j] += v;
        cq[j] += v * v;
      }
#pragma unroll
  for (int j = 0; j < 4; ++j) {
    float ss = cs[j], qq = cq[j];
    ss += __shfl_xor(ss, 16, 64);
    qq += __shfl_xor(qq, 16, 64);
    ss += __shfl_xor(ss, 32, 64);
    qq += __shfl_xor(qq, 32, 64);
    if (lane < 16) {
      int c = n0 + (j >> 1) * 128 + (j & 1) * 64 + wc * 16 + lane;
      atomicAdd(&st[c], ss);
      atomicAdd(&st[N + c], qq);
    }
  }
}

// h = relu(scale*z + shift) with coef computed in-kernel from raw sums;
// write hi/lo bf16 pairs [NB, 2048]. Block = 8 rows x 1024 cols.
__global__ void bn_relu_split_kernel(const float* __restrict__ z, const float* __restrict__ st,
                                     const float* __restrict__ g, const float* __restrict__ b,
                                     u16* __restrict__ out) {
  const int tid = threadIdx.x;
  const int r0 = blockIdx.x * 8;
  const int c0 = tid * 4;
  const float invB = 1.f / (float)NB;
  float4 sv = *reinterpret_cast<const float4*>(st + c0);
  float4 qv = *reinterpret_cast<const float4*>(st + 1024 + c0);
  float4 gv = *reinterpret_cast<const float4*>(g + c0);
  float4 bv = *reinterpret_cast<const float4*>(b + c0);
  float sc[4], sh[4];
  {
    float s[4] = {sv.x, sv.y, sv.z, sv.w};
    float qa[4] = {qv.x, qv.y, qv.z, qv.w};
    float gg[4] = {gv.x, gv.y, gv.z, gv.w};
    float bb[4] = {bv.x, bv.y, bv.z, bv.w};
#pragma unroll
    for (int e = 0; e < 4; ++e) {
      float mu = s[e] * invB;
      float var = fmaxf(qa[e] * invB - mu * mu, 0.f);
      sc[e] = gg[e] * rsqrtf(var + 1e-5f);
      sh[e] = bb[e] - mu * sc[e];
    }
  }
#pragma unroll
  for (int r = 0; r < 8; ++r) {
    float4 v = *reinterpret_cast<const float4*>(z + (size_t)(r0 + r) * 1024 + c0);
    float hv[4] = {fmaxf(v.x * sc[0] + sh[0], 0.f), fmaxf(v.y * sc[1] + sh[1], 0.f),
                   fmaxf(v.z * sc[2] + sh[2], 0.f), fmaxf(v.w * sc[3] + sh[3], 0.f)};
    u16x8 o;
#pragma unroll
    for (int e = 0; e < 4; ++e) {
      u16 hi = f2bf(hv[e]);
      u16 lo = f2bf(hv[e] - bf2f(hi));
      o[2 * e] = hi;
      o[2 * e + 1] = lo;
    }
    *reinterpret_cast<u16x8*>(out + (size_t)(r0 + r) * 2048 + tid * 8) = o;
  }
}

// layer 3: BN2 coef computed in-kernel from raw sums, z3 = h2n @ sign(W3)^T,
// relu, softmax. 32 rows per block (8 iterations x 4 waves) to amortize the
// 40KB W3 LDS staging 8x vs the 4-row version.
__global__ void gemm3_softmax_kernel(const float* __restrict__ r2, const float* __restrict__ st,
                                     const float* __restrict__ g, const float* __restrict__ b,
                                     const float* __restrict__ W3, float* __restrict__ out) {
  __shared__ float s3[10 * 1024];
  __shared__ float cf[2048];
  const int tid = threadIdx.x;
  for (int i = tid; i < 10 * 1024; i += 256) {
    float wv = W3[i];
    s3[i] = wv > 0.f ? 1.f : (wv < 0.f ? -1.f : 0.f);
  }
  const float invB = 1.f / (float)NB;
  for (int i = tid; i < 1024; i += 256) {
    float mu = st[i] * invB;
    float var = fmaxf(st[1024 + i] * invB - mu * mu, 0.f);
    float sc = g[i] * rsqrtf(var + 1e-5f);
    cf[i] = sc;
    cf[1024 + i] = b[i] - mu * sc;
  }
  __syncthreads();
  const int lane = tid & 63;
  const int wid = tid >> 6;
  for (int it = 0; it < 8; ++it) {
    const size_t row = (size_t)blockIdx.x * 32 + it * 4 + wid;
    float h[16];
#pragma unroll
    for (int j = 0; j < 4; ++j) {
      float4 v = *reinterpret_cast<const float4*>(r2 + row * 1024 + j * 256 + lane * 4);
      float4 sc = *reinterpret_cast<const float4*>(&cf[j * 256 + lane * 4]);
      float4 sh = *reinterpret_cast<const float4*>(&cf[1024 + j * 256 + lane * 4]);
      h[j * 4 + 0] = v.x * sc.x + sh.x;
      h[j * 4 + 1] = v.y * sc.y + sh.y;
      h[j * 4 + 2] = v.z * sc.z + sh.z;
      h[j * 4 + 3] = v.w * sc.w + sh.w;
    }
    float l[10];
#pragma unroll
    for (int c = 0; c < 10; ++c) {
      float a = 0.f;
#pragma unroll
      for (int j = 0; j < 4; ++j) {
        float4 s = *reinterpret_cast<const float4*>(&s3[c * 1024 + j * 256 + lane * 4]);
        a += h[j * 4 + 0] * s.x + h[j * 4 + 1] * s.y + h[j * 4 + 2] * s.z + h[j * 4 + 3] * s.w;
      }
#pragma unroll
      for (int m = 1; m < 64; m <<= 1) a += __shfl_xor(a, m, 64);
      l[c] = fmaxf(a, 0.f);
    }
    float mx = l[0];
#pragma unroll
    for (int c = 1; c < 10; ++c) mx = fmaxf(mx, l[c]);
    float se = 0.f;
#pragma unroll
    for (int c = 0; c < 10; ++c) {
      l[c] = expf(l[c] - mx);
      se += l[c];
    }
    float inv = 1.f / se;
    float pv = 0.f;
#pragma unroll
    for (int c = 0; c < 10; ++c)
      if (lane == c) pv = l[c] * inv;
    if (lane < 10) out[row * 10 + lane] = pv;
  }
}

extern "C" void kernel_launch(void* const* d_in, const int* in_sizes, int n_in,
                              void* d_out, int out_size, void* d_ws, size_t ws_size,
                              hipStream_t stream) {
  const float* x = (const float*)d_in[0];
  const float* W1 = (const float*)d_in[1];
  const float* g1 = (const float*)d_in[2];
  const float* b1 = (const float*)d_in[3];
  const float* W2 = (const float*)d_in[4];
  const float* g2 = (const float*)d_in[5];
  const float* b2 = (const float*)d_in[6];
  const float* W3 = (const float*)d_in[7];
  float* out = (float*)d_out;

  char* ws = (char*)d_ws;
  size_t off = 0;
  auto alloc = [&](size_t bytes) -> char* {
    char* p = ws + off;
    off += (bytes + 255) & ~(size_t)255;
    return p;
  };
  u16* R1 = (u16*)alloc((size_t)NB * 2048 * 2);      // xhl (stride 1664) then h1hl (stride 2048)
  float* R2 = (float*)alloc((size_t)NB * 1024 * 4);  // z1 then r2
  u16* sW1 = (u16*)alloc((size_t)1024 * KP1 * 2);
  u16* sW2 = (u16*)alloc((size_t)1024 * K2 * 2);
  float* st1 = (float*)alloc(2048 * 4);              // st1, st2 adjacent -> one memset
  float* st2 = (float*)alloc(2048 * 4);

  hipMemsetAsync(st1, 0, 2 * 2048 * 4 + 256, stream);

  prep_x_kernel<<<(NB * 208) / 256, 256, 0, stream>>>(x, R1);
  prep_wdup_kernel<<<(1024 * 208) / 256, 256, 0, stream>>>(W1, sW1, 196, 208);
  prep_wdup_kernel<<<(1024 * 256) / 256, 256, 0, stream>>>(W2, sW2, 256, 256);

  gemm256_kernel<0><<<(NB / 256) * (1024 / 256), 512, 131072, stream>>>(R1, sW1, R2, st1, NB,
                                                                        1024, KP1, 4);
  bn_relu_split_kernel<<<NB / 8, 256, 0, stream>>>(R2, st1, g1, b1, R1);

  gemm256_kernel<1><<<(NB / 256) * (1024 / 256), 512, 131072, stream>>>(R1, sW2, R2, st2, NB,
                                                                        1024, K2, 4);
  gemm3_softmax_kernel<<<NB / 32, 256, 0, stream>>>(R2, st2, g2, b2, W3, out);
}

// Round 9
// 519.699 us; speedup vs baseline: 1.3440x; 1.3440x over previous
//
#include <hip/hip_runtime.h>
#include <stdint.h>

// Binarized MLP forward, MI355X.
// GEMMs: round-6 measured-best: 256x256-tile, BK=32, 8-wave, 4-LDS-buffer
// stage-3-ahead pipeline, COUNTED vmcnt(8) waits (T3+T4), T2 read-swizzle,
// T5 setprio. bf16 hi/lo split inputs (exact sign() weights), fused BN-stats
// epilogue. gemm3: lean L1-resident sign(W3) bf16, cf-only LDS (8KB).

using u16 = unsigned short;
typedef u16 u16x4 __attribute__((ext_vector_type(4)));
typedef u16 u16x8 __attribute__((ext_vector_type(8)));
typedef __bf16 bf16x8 __attribute__((ext_vector_type(8)));
typedef float f32x4 __attribute__((ext_vector_type(4)));

#define NB 32768
#define KP1 1664   // 784*2 = 1568 padded to 52*32
#define K2 2048

__device__ __forceinline__ u16 f2bf(float f) {
  uint32_t u = __float_as_uint(f);
  u += 0x7FFF + ((u >> 16) & 1);  // round-to-nearest-even
  return (u16)(u >> 16);
}
__device__ __forceinline__ float bf2f(u16 h) {
  return __uint_as_float(((uint32_t)h) << 16);
}

__device__ __forceinline__ void gload_lds16(const void* g, void* l) {
  __builtin_amdgcn_global_load_lds(
      (const __attribute__((address_space(1))) uint32_t*)g,
      (__attribute__((address_space(3))) uint32_t*)l, 16, 0, 0);
}

// x [NB,784] fp32 -> xhl [NB,1664] bf16 (hi,lo interleaved, cols 1568.. zero)
__global__ void prep_x_kernel(const float* __restrict__ x, u16* __restrict__ xhl) {
  int gid = blockIdx.x * 256 + threadIdx.x;  // NB*208 threads
  int row = gid / 208, slot = gid % 208;
  u16x8 o = {0, 0, 0, 0, 0, 0, 0, 0};
  if (slot < 196) {
    float4 v = *reinterpret_cast<const float4*>(x + (size_t)row * 784 + slot * 4);
    float vv[4] = {v.x, v.y, v.z, v.w};
#pragma unroll
    for (int e = 0; e < 4; ++e) {
      u16 hi = f2bf(vv[e]);
      u16 lo = f2bf(vv[e] - bf2f(hi));
      o[2 * e] = hi;
      o[2 * e + 1] = lo;
    }
  }
  *reinterpret_cast<u16x8*>(xhl + (size_t)row * KP1 + slot * 8) = o;
}

// W [rows, in_slots*4] fp32 -> sign duplicated [rows, out_slots*8] bf16
__global__ void prep_wdup_kernel(const float* __restrict__ w, u16* __restrict__ o,
                                 int in_slots, int out_slots) {
  int gid = blockIdx.x * 256 + threadIdx.x;
  int row = gid / out_slots, slot = gid % out_slots;
  u16x8 r = {0, 0, 0, 0, 0, 0, 0, 0};
  if (slot < in_slots) {
    float4 v = *reinterpret_cast<const float4*>(w + (size_t)row * (in_slots * 4) + slot * 4);
    float vv[4] = {v.x, v.y, v.z, v.w};
#pragma unroll
    for (int e = 0; e < 4; ++e) {
      u16 s = vv[e] > 0.f ? (u16)0x3F80 : (vv[e] < 0.f ? (u16)0xBF80 : (u16)0);
      r[2 * e] = s;
      r[2 * e + 1] = s;
    }
  }
  *reinterpret_cast<u16x8*>(o + (size_t)row * (out_slots * 8) + slot * 8) = r;
}

// W3 [10,1024] fp32 -> bf16 signs (20 KB, L1/L2-resident for gemm3)
__global__ void prep_w3_kernel(const float* __restrict__ w, u16* __restrict__ o) {
  int i = blockIdx.x * 256 + threadIdx.x;
  if (i < 10 * 1024) {
    float v = w[i];
    o[i] = v > 0.f ? (u16)0x3F80 : (v < 0.f ? (u16)0xBF80 : (u16)0);
  }
}

// ds_read_b128 with literal offset
#define DSR(D, A, OFF) \
  asm volatile("ds_read_b128 %0, %1 offset:%c2" : "=v"(D) : "v"(A), "i"(OFF))

// Stage tile T's A-halves (2 gloads) or B-halves into buffer BB.
// LDS dest linear (wave base + lane*16); source col pre-swizzled (rule #21).
#define STAGE_A(BB, T)                                                         \
  do {                                                                         \
    gload_lds16(sA + (size_t)(T)*64, smem + (BB)*32768 + w * 1024);            \
    gload_lds16(sA + (size_t)(T)*64 + 256 * (size_t)K,                         \
                smem + (BB)*32768 + 8192 + w * 1024);                          \
  } while (0)
#define STAGE_B(BB, T)                                                         \
  do {                                                                         \
    gload_lds16(sB + (size_t)(T)*64, smem + (BB)*32768 + 16384 + w * 1024);    \
    gload_lds16(sB + (size_t)(T)*64 + 256 * (size_t)K,                         \
                smem + (BB)*32768 + 24576 + w * 1024);                         \
  } while (0)

// One phase: 8 ds_read_b128 (4 A-frags of m-half MH + 4 B-frags) || staging,
// then lgkmcnt(0) + sched_barrier (rule #18) + setprio-wrapped 16 MFMA.
#define PHASE(BUFB, MH, PRE)                                                              \
  do {                                                                                    \
    bf16x8 a0, a1, a2, a3, b0, b1, b2, b3;                                                \
    const uint32_t aA = (BUFB) + baseA + (MH)*4096;                                       \
    const uint32_t aB = (BUFB) + baseB;                                                   \
    DSR(a0, aA, 0);                                                                       \
    DSR(a1, aA, 1024);                                                                    \
    DSR(a2, aA, 2048);                                                                    \
    DSR(a3, aA, 3072);                                                                    \
    DSR(b0, aB, 0);                                                                       \
    DSR(b1, aB, 1024);                                                                    \
    DSR(b2, aB, 2048);                                                                    \
    DSR(b3, aB, 3072);                                                                    \
    PRE;                                                                                  \
    asm volatile("s_waitcnt lgkmcnt(0)" ::: "memory");                                    \
    __builtin_amdgcn_sched_barrier(0);                                                    \
    __builtin_amdgcn_s_setprio(1);                                                        \
    acc[(MH)*4 + 0][0] = __builtin_amdgcn_mfma_f32_16x16x32_bf16(a0, b0, acc[(MH)*4 + 0][0], 0, 0, 0); \
    acc[(MH)*4 + 0][1] = __builtin_amdgcn_mfma_f32_16x16x32_bf16(a0, b1, acc[(MH)*4 + 0][1], 0, 0, 0); \
    acc[(MH)*4 + 0][2] = __builtin_amdgcn_mfma_f32_16x16x32_bf16(a0, b2, acc[(MH)*4 + 0][2], 0, 0, 0); \
    acc[(MH)*4 + 0][3] = __builtin_amdgcn_mfma_f32_16x16x32_bf16(a0, b3, acc[(MH)*4 + 0][3], 0, 0, 0); \
    acc[(MH)*4 + 1][0] = __builtin_amdgcn_mfma_f32_16x16x32_bf16(a1, b0, acc[(MH)*4 + 1][0], 0, 0, 0); \
    acc[(MH)*4 + 1][1] = __builtin_amdgcn_mfma_f32_16x16x32_bf16(a1, b1, acc[(MH)*4 + 1][1], 0, 0, 0); \
    acc[(MH)*4 + 1][2] = __builtin_amdgcn_mfma_f32_16x16x32_bf16(a1, b2, acc[(MH)*4 + 1][2], 0, 0, 0); \
    acc[(MH)*4 + 1][3] = __builtin_amdgcn_mfma_f32_16x16x32_bf16(a1, b3, acc[(MH)*4 + 1][3], 0, 0, 0); \
    acc[(MH)*4 + 2][0] = __builtin_amdgcn_mfma_f32_16x16x32_bf16(a2, b0, acc[(MH)*4 + 2][0], 0, 0, 0); \
    acc[(MH)*4 + 2][1] = __builtin_amdgcn_mfma_f32_16x16x32_bf16(a2, b1, acc[(MH)*4 + 2][1], 0, 0, 0); \
    acc[(MH)*4 + 2][2] = __builtin_amdgcn_mfma_f32_16x16x32_bf16(a2, b2, acc[(MH)*4 + 2][2], 0, 0, 0); \
    acc[(MH)*4 + 2][3] = __builtin_amdgcn_mfma_f32_16x16x32_bf16(a2, b3, acc[(MH)*4 + 2][3], 0, 0, 0); \
    acc[(MH)*4 + 3][0] = __builtin_amdgcn_mfma_f32_16x16x32_bf16(a3, b0, acc[(MH)*4 + 3][0], 0, 0, 0); \
    acc[(MH)*4 + 3][1] = __builtin_amdgcn_mfma_f32_16x16x32_bf16(a3, b1, acc[(MH)*4 + 3][1], 0, 0, 0); \
    acc[(MH)*4 + 3][2] = __builtin_amdgcn_mfma_f32_16x16x32_bf16(a3, b2, acc[(MH)*4 + 3][2], 0, 0, 0); \
    acc[(MH)*4 + 3][3] = __builtin_amdgcn_mfma_f32_16x16x32_bf16(a3, b3, acc[(MH)*4 + 3][3], 0, 0, 0); \
    __builtin_amdgcn_s_setprio(0);                                                        \
  } while (0)

#define VW(N) asm volatile("s_waitcnt vmcnt(" #N ")" ::: "memory")

// C[M,N] = A[M,K]*Bm[N,K]^T, bf16 in fp32 out, 256x256 tile, 8 waves (2x4),
// dynamic LDS 128 KiB (4 x 32KB tile buffers). Fused column sum/sumsq epilogue.
template <int RELU>
__launch_bounds__(512, 2) __global__
void gemm256_kernel(const u16* __restrict__ A, const u16* __restrict__ Bm,
                    float* __restrict__ C, float* __restrict__ st,
                    int M, int N, int K, int nbn) {
  extern __shared__ char smem[];
  typedef __attribute__((address_space(3))) char lds_char;
  const uint32_t ldsbase = (uint32_t)(uintptr_t)(lds_char*)smem;
  const int tid = threadIdx.x;
  const int lane = tid & 63;
  const int w = tid >> 6;
  const int wr = w >> 2;  // 0..1 (m-half, 128 rows)
  const int wc = w & 3;   // 0..3 (n-quarter, 64 cols)
  const int cpx = gridDim.x >> 3;
  const int bid = (blockIdx.x & 7) * cpx + (blockIdx.x >> 3);
  const int m0 = (bid / nbn) * 256;
  const int n0 = (bid % nbn) * 256;
  const int nt = K >> 5;  // BK=32 tiles

  f32x4 acc[8][4];
  const f32x4 z4 = {0.f, 0.f, 0.f, 0.f};
#pragma unroll
  for (int i = 0; i < 8; ++i)
#pragma unroll
    for (int j = 0; j < 4; ++j) acc[i][j] = z4;

  // staging source: thread covers row (i*128 + w*16 + lane/4), col-slot lane&3,
  // source col pre-swizzled by ((lane>>3)&3) == (row>>1)&3 (rule #21).
  const int colL = 8 * ((lane & 3) ^ ((lane >> 3) & 3));  // elements
  const int srow = w * 16 + (lane >> 2);
  const char* sA = (const char*)(A + (size_t)(m0 + srow) * K + colL);
  const char* sB = (const char*)(Bm + (size_t)(n0 + srow) * K + colL);

  // read-side per-lane base: row lr within frag, K-quarter q, swizzled slot
  const int lr = lane & 15;
  const int q = lane >> 4;
  const uint32_t rdoff = (uint32_t)(lr * 64 + ((q ^ ((lr >> 1) & 3)) * 16));
  const uint32_t baseA = (uint32_t)(wr * 8192) + rdoff;           // + MH*4096 + mf*1024
  const uint32_t baseB = 16384u + (uint32_t)(wc * 4096) + rdoff;  // + nf*1024

  // prologue: stage tiles 0,1,2 into buffers 0,1,2
  STAGE_A(0, 0);
  STAGE_B(0, 0);
  STAGE_A(1, 1);
  STAGE_B(1, 1);
  STAGE_A(2, 2);
  STAGE_B(2, 2);

  // main loop: entry counted wait (tile t's 4 loads = oldest of 12), 1 barrier,
  // stage tile t+3 spread across the 2 phases.
  for (int t = 0; t < nt - 3; ++t) {
    const uint32_t bufb = ldsbase + (uint32_t)((t & 3) * 32768);
    const int bs = (t + 3) & 3;
    VW(8);
    __builtin_amdgcn_s_barrier();
    PHASE(bufb, 0, STAGE_A(bs, t + 3));
    PHASE(bufb, 1, STAGE_B(bs, t + 3));
  }
  // epilogue: tiles nt-3 (12 outstanding), nt-2 (8), nt-1 (4)
  {
    const int t = nt - 3;
    const uint32_t bufb = ldsbase + (uint32_t)((t & 3) * 32768);
    VW(8);
    __builtin_amdgcn_s_barrier();
    PHASE(bufb, 0, ;);
    PHASE(bufb, 1, ;);
  }
  {
    const int t = nt - 2;
    const uint32_t bufb = ldsbase + (uint32_t)((t & 3) * 32768);
    VW(4);
    __builtin_amdgcn_s_barrier();
    PHASE(bufb, 0, ;);
    PHASE(bufb, 1, ;);
  }
  {
    const int t = nt - 1;
    const uint32_t bufb = ldsbase + (uint32_t)((t & 3) * 32768);
    VW(0);
    __builtin_amdgcn_s_barrier();
    PHASE(bufb, 0, ;);
    PHASE(bufb, 1, ;);
  }

  // epilogue: C-write + fused column stats.
  // C/D layout (m89-verified): col = lane&15, row = (lane>>4)*4 + i
  const int rq = lane >> 4;
  float cs[4] = {0.f, 0.f, 0.f, 0.f};
  float cq[4] = {0.f, 0.f, 0.f, 0.f};
#pragma unroll
  for (int mf = 0; mf < 8; ++mf)
#pragma unroll
    for (int nf = 0; nf < 4; ++nf)
#pragma unroll
      for (int i = 0; i < 4; ++i) {
        int r = m0 + wr * 128 + mf * 16 + rq * 4 + i;
        int cc = n0 + wc * 64 + nf * 16 + lr;
        float v = acc[mf][nf][i];
        if (RELU) v = fmaxf(v, 0.f);
        C[(size_t)r * N + cc] = v;
        cs[nf] += v;
        cq[nf] += v * v;
      }
#pragma unroll
  for (int nf = 0; nf < 4; ++nf) {
    float ss = cs[nf], qq = cq[nf];
    ss += __shfl_xor(ss, 16, 64);
    qq += __shfl_xor(qq, 16, 64);
    ss += __shfl_xor(ss, 32, 64);
    qq += __shfl_xor(qq, 32, 64);
    if (lane < 16) {
      int c = n0 + wc * 64 + nf * 16 + lane;
      atomicAdd(&st[c], ss);
      atomicAdd(&st[N + c], qq);
    }
  }
}

// h = relu(scale*z + shift) with coef computed in-kernel from raw sums;
// write hi/lo bf16 pairs [NB, 2048]. Block = 8 rows x 1024 cols.
__global__ void bn_relu_split_kernel(const float* __restrict__ z, const float* __restrict__ st,
                                     const float* __restrict__ g, const float* __restrict__ b,
                                     u16* __restrict__ out) {
  const int tid = threadIdx.x;
  const int r0 = blockIdx.x * 8;
  const int c0 = tid * 4;
  const float invB = 1.f / (float)NB;
  float4 sv = *reinterpret_cast<const float4*>(st + c0);
  float4 qv = *reinterpret_cast<const float4*>(st + 1024 + c0);
  float4 gv = *reinterpret_cast<const float4*>(g + c0);
  float4 bv = *reinterpret_cast<const float4*>(b + c0);
  float sc[4], sh[4];
  {
    float s[4] = {sv.x, sv.y, sv.z, sv.w};
    float qa[4] = {qv.x, qv.y, qv.z, qv.w};
    float gg[4] = {gv.x, gv.y, gv.z, gv.w};
    float bb[4] = {bv.x, bv.y, bv.z, bv.w};
#pragma unroll
    for (int e = 0; e < 4; ++e) {
      float mu = s[e] * invB;
      float var = fmaxf(qa[e] * invB - mu * mu, 0.f);
      sc[e] = gg[e] * rsqrtf(var + 1e-5f);
      sh[e] = bb[e] - mu * sc[e];
    }
  }
#pragma unroll
  for (int r = 0; r < 8; ++r) {
    float4 v = *reinterpret_cast<const float4*>(z + (size_t)(r0 + r) * 1024 + c0);
    float hv[4] = {fmaxf(v.x * sc[0] + sh[0], 0.f), fmaxf(v.y * sc[1] + sh[1], 0.f),
                   fmaxf(v.z * sc[2] + sh[2], 0.f), fmaxf(v.w * sc[3] + sh[3], 0.f)};
    u16x8 o;
#pragma unroll
    for (int e = 0; e < 4; ++e) {
      u16 hi = f2bf(hv[e]);
      u16 lo = f2bf(hv[e] - bf2f(hi));
      o[2 * e] = hi;
      o[2 * e + 1] = lo;
    }
    *reinterpret_cast<u16x8*>(out + (size_t)(r0 + r) * 2048 + tid * 8) = o;
  }
}

// layer 3: BN2 coef from raw sums (8KB LDS only), z3 = h2n @ signW3^T (bf16
// signs read from global, L1-resident 20KB), relu, softmax. 4 rows/block,
// 8192 blocks -> full wave-slot occupancy (8 blocks/CU), max TLP.
__global__ void gemm3_softmax_kernel(const float* __restrict__ r2, const float* __restrict__ st,
                                     const float* __restrict__ g, const float* __restrict__ b,
                                     const u16* __restrict__ w3s, float* __restrict__ out) {
  __shared__ float cf[2048];
  const int tid = threadIdx.x;
  const float invB = 1.f / (float)NB;
  for (int i = tid; i < 1024; i += 256) {
    float mu = st[i] * invB;
    float var = fmaxf(st[1024 + i] * invB - mu * mu, 0.f);
    float sc = g[i] * rsqrtf(var + 1e-5f);
    cf[i] = sc;
    cf[1024 + i] = b[i] - mu * sc;
  }
  __syncthreads();
  const int lane = tid & 63;
  const int wid = tid >> 6;
  const size_t row = (size_t)blockIdx.x * 4 + wid;
  float h[16];
#pragma unroll
  for (int j = 0; j < 4; ++j) {
    float4 v = *reinterpret_cast<const float4*>(r2 + row * 1024 + j * 256 + lane * 4);
    float4 sc = *reinterpret_cast<const float4*>(&cf[j * 256 + lane * 4]);
    float4 sh = *reinterpret_cast<const float4*>(&cf[1024 + j * 256 + lane * 4]);
    h[j * 4 + 0] = v.x * sc.x + sh.x;
    h[j * 4 + 1] = v.y * sc.y + sh.y;
    h[j * 4 + 2] = v.z * sc.z + sh.z;
    h[j * 4 + 3] = v.w * sc.w + sh.w;
  }
  float l[10];
#pragma unroll
  for (int c = 0; c < 10; ++c) {
    float a = 0.f;
#pragma unroll
    for (int j = 0; j < 4; ++j) {
      u16x4 s = *reinterpret_cast<const u16x4*>(w3s + c * 1024 + j * 256 + lane * 4);
      a += h[j * 4 + 0] * bf2f(s[0]) + h[j * 4 + 1] * bf2f(s[1]) +
           h[j * 4 + 2] * bf2f(s[2]) + h[j * 4 + 3] * bf2f(s[3]);
    }
#pragma unroll
    for (int m = 1; m < 64; m <<= 1) a += __shfl_xor(a, m, 64);
    l[c] = fmaxf(a, 0.f);
  }
  float mx = l[0];
#pragma unroll
  for (int c = 1; c < 10; ++c) mx = fmaxf(mx, l[c]);
  float se = 0.f;
#pragma unroll
  for (int c = 0; c < 10; ++c) {
    l[c] = expf(l[c] - mx);
    se += l[c];
  }
  float inv = 1.f / se;
  float pv = 0.f;
#pragma unroll
  for (int c = 0; c < 10; ++c)
    if (lane == c) pv = l[c] * inv;
  if (lane < 10) out[row * 10 + lane] = pv;
}

extern "C" void kernel_launch(void* const* d_in, const int* in_sizes, int n_in,
                              void* d_out, int out_size, void* d_ws, size_t ws_size,
                              hipStream_t stream) {
  const float* x = (const float*)d_in[0];
  const float* W1 = (const float*)d_in[1];
  const float* g1 = (const float*)d_in[2];
  const float* b1 = (const float*)d_in[3];
  const float* W2 = (const float*)d_in[4];
  const float* g2 = (const float*)d_in[5];
  const float* b2 = (const float*)d_in[6];
  const float* W3 = (const float*)d_in[7];
  float* out = (float*)d_out;

  char* ws = (char*)d_ws;
  size_t off = 0;
  auto alloc = [&](size_t bytes) -> char* {
    char* p = ws + off;
    off += (bytes + 255) & ~(size_t)255;
    return p;
  };
  u16* R1 = (u16*)alloc((size_t)NB * 2048 * 2);      // xhl (stride 1664) then h1hl (stride 2048)
  float* R2 = (float*)alloc((size_t)NB * 1024 * 4);  // z1 then r2
  u16* sW1 = (u16*)alloc((size_t)1024 * KP1 * 2);
  u16* sW2 = (u16*)alloc((size_t)1024 * K2 * 2);
  u16* w3s = (u16*)alloc(10 * 1024 * 2);
  float* st1 = (float*)alloc(2048 * 4);              // st1, st2 adjacent -> one memset
  float* st2 = (float*)alloc(2048 * 4);

  hipMemsetAsync(st1, 0, 2 * 2048 * 4 + 256, stream);

  prep_x_kernel<<<(NB * 208) / 256, 256, 0, stream>>>(x, R1);
  prep_wdup_kernel<<<(1024 * 208) / 256, 256, 0, stream>>>(W1, sW1, 196, 208);
  prep_wdup_kernel<<<(1024 * 256) / 256, 256, 0, stream>>>(W2, sW2, 256, 256);
  prep_w3_kernel<<<40, 256, 0, stream>>>(W3, w3s);

  gemm256_kernel<0><<<(NB / 256) * (1024 / 256), 512, 131072, stream>>>(R1, sW1, R2, st1, NB,
                                                                        1024, KP1, 4);
  bn_relu_split_kernel<<<NB / 8, 256, 0, stream>>>(R2, st1, g1, b1, R1);

  gemm256_kernel<1><<<(NB / 256) * (1024 / 256), 512, 131072, stream>>>(R1, sW2, R2, st2, NB,
                                                                        1024, K2, 4);
  gemm3_softmax_kernel<<<NB / 4, 256, 0, stream>>>(R2, st2, g2, b2, w3s, out);
}